// Round 2
// baseline (387.010 us; speedup 1.0000x reference)
//
#include <hip/hip_runtime.h>
#include <hip/hip_bf16.h>
#include <math.h>

#define BDIM 512
#define DDIM 512
#define CDIM 100000
#define NC 64
#define BK 64
#define NSLICE (DDIM / BK)              // 8
#define NCHUNK ((CDIM + NC - 1) / NC)   // 1563

typedef __attribute__((ext_vector_type(8))) short short8;
typedef __attribute__((ext_vector_type(4))) float f32x4;

__device__ __forceinline__ unsigned short f2bf(float f) {
  unsigned int u = __builtin_bit_cast(unsigned int, f);
  u = (u + 0x7FFFu + ((u >> 16) & 1u)) >> 16;   // RNE
  return (unsigned short)u;
}

// ---- kernel 1: L2-normalize feature rows, emit bf16 [B][D] ----
__global__ void k_rownorm(const float* __restrict__ x, unsigned short* __restrict__ a) {
  const int b = blockIdx.x;
  const int tid = threadIdx.x;
  const float* row = x + (size_t)b * DDIM;
  float v0 = row[tid], v1 = row[tid + 256];
  float ss = v0 * v0 + v1 * v1;
  #pragma unroll
  for (int m = 1; m < 64; m <<= 1) ss += __shfl_xor(ss, m);
  __shared__ float sred[4];
  __shared__ float sinv;
  if ((tid & 63) == 0) sred[tid >> 6] = ss;
  __syncthreads();
  if (tid == 0) {
    float s = sred[0] + sred[1] + sred[2] + sred[3];
    sinv = 1.f / fmaxf(sqrtf(s), 1e-12f);
  }
  __syncthreads();
  const float inv = sinv;
  a[(size_t)b * DDIM + tid] = f2bf(v0 * inv);
  a[(size_t)b * DDIM + tid + 256] = f2bf(v1 * inv);
}

// ---- kernel 2: fused colnorm + GEMM + margin + per-chunk LSE partials ----
// Double-buffered BK=64 K-slices; async-STAGE split (issue-early / commit-late).
__global__ __launch_bounds__(512, 4)
void k_main(const unsigned short* __restrict__ a,
            const float* __restrict__ w,
            const long long* __restrict__ label,
            float2* __restrict__ part,
            float* __restrict__ labellogit) {
  __shared__ __align__(16) unsigned short wlds[2][NC][BK];  // 2 x 8 KB bf16, XOR-swizzled
  __shared__ float ssred[32][NC];                           // 8 KB
  __shared__ float invwn_sh[NC];

  const int t = threadIdx.x;
  const int chunk = blockIdx.x;
  const int c0 = chunk * NC;
  const bool tailblk = (c0 + NC > CDIM);

  // staging mapping: thread -> col quad (4 consecutive cols), d-group
  const int cq4 = (t & 15) * 4;   // col base within chunk
  const int dg  = t >> 4;         // 0..31, row within half-slice
  float ssp0 = 0.f, ssp1 = 0.f, ssp2 = 0.f, ssp3 = 0.f;

  // compute mapping
  const int wave = t >> 6;
  const int lane = t & 63;
  const int lhi = lane >> 4;   // 0..3
  const int llo = lane & 15;   // 0..15

  // ---- stage helpers ----
  float4 p0, p1;   // in-flight slice data
  auto issue = [&](int s) {
    const size_t d0 = (size_t)(s * BK + dg) * CDIM + c0 + cq4;
    const size_t d1 = d0 + (size_t)32 * CDIM;
    if (!tailblk) {
      p0 = *reinterpret_cast<const float4*>(w + d0);
      p1 = *reinterpret_cast<const float4*>(w + d1);
    } else {
      #pragma unroll
      for (int j = 0; j < 4; j++) {
        const bool v = (c0 + cq4 + j) < CDIM;
        p0[j] = v ? w[d0 + j] : 0.f;
        p1[j] = v ? w[d1 + j] : 0.f;
      }
    }
  };
  auto commit = [&](int buf) {
    ssp0 += p0.x * p0.x + p1.x * p1.x;
    ssp1 += p0.y * p0.y + p1.y * p1.y;
    ssp2 += p0.z * p0.z + p1.z * p1.z;
    ssp3 += p0.w * p0.w + p1.w * p1.w;
    #pragma unroll
    for (int j = 0; j < 4; j++) {
      const int c = cq4 + j;
      const int m = (c & 7) << 3;
      wlds[buf][c][dg ^ m]        = f2bf(p0[j]);
      wlds[buf][c][(dg + 32) ^ m] = f2bf(p1[j]);
    }
  };

  f32x4 acc[4][4];
  #pragma unroll
  for (int i = 0; i < 4; i++)
    #pragma unroll
    for (int j = 0; j < 4; j++)
      acc[i][j] = (f32x4){0.f, 0.f, 0.f, 0.f};

  const unsigned short* ab = a + (size_t)(wave * 64 + llo) * DDIM + (lhi << 3);

  // ---- prologue: stage slice 0 ----
  issue(0);
  commit(0);
  __syncthreads();

  int buf = 0;
  for (int s = 0; s < NSLICE; s++) {
    const bool more = (s + 1 < NSLICE);
    if (more) issue(s + 1);                 // loads in flight across compute

    #pragma unroll
    for (int half = 0; half < 2; half++) {
      const int kk = s * BK + half * 32;    // global k
      const int kloc = half * 32 + (lhi << 3);
      short8 af[4], bfr[4];
      #pragma unroll
      for (int rf = 0; rf < 4; rf++)
        af[rf] = *reinterpret_cast<const short8*>(ab + kk + rf * 16 * DDIM);
      #pragma unroll
      for (int cf = 0; cf < 4; cf++) {
        const int c = cf * 16 + llo;
        bfr[cf] = *reinterpret_cast<const short8*>(&wlds[buf][c][kloc ^ ((c & 7) << 3)]);
      }
      #pragma unroll
      for (int rf = 0; rf < 4; rf++)
        #pragma unroll
        for (int cf = 0; cf < 4; cf++)
          acc[rf][cf] = __builtin_amdgcn_mfma_f32_16x16x32_bf16(af[rf], bfr[cf], acc[rf][cf], 0, 0, 0);
    }

    if (more) commit(buf ^ 1);              // vmcnt wait lands after MFMAs
    __syncthreads();
    buf ^= 1;
  }

  // ---- column-norm reduce ----
  *reinterpret_cast<float4*>(&ssred[dg][cq4]) = (float4){ssp0, ssp1, ssp2, ssp3};
  __syncthreads();
  if (t < NC) {
    float s = 0.f;
    #pragma unroll
    for (int i = 0; i < 32; i++) s += ssred[i][t];
    invwn_sh[t] = 1.f / fmaxf(sqrtf(s), 1e-12f);
  }
  __syncthreads();

  // ---- epilogue: logits -> per-row (max, sumexp) over this chunk's 64 classes ----
  #pragma unroll
  for (int rf = 0; rf < 4; rf++) {
    #pragma unroll
    for (int r = 0; r < 4; r++) {
      const int row = wave * 64 + rf * 16 + (lhi << 2) + r;
      const int lab = (int)label[row];
      float vals[4];
      float mloc = -INFINITY;
      #pragma unroll
      for (int cf = 0; cf < 4; cf++) {
        const int cg = c0 + cf * 16 + llo;
        float cs = acc[rf][cf][r] * invwn_sh[cf * 16 + llo];
        cs = fminf(fmaxf(cs, -1.f), 1.f);
        float lg = 64.f * cs;
        if (cg == lab) { lg = 64.f * (cs - 0.35f); labellogit[row] = lg; }
        if (cg >= CDIM) lg = -INFINITY;
        vals[cf] = lg;
        mloc = fmaxf(mloc, lg);
      }
      float m = mloc;
      #pragma unroll
      for (int msk = 1; msk < 16; msk <<= 1) m = fmaxf(m, __shfl_xor(m, msk));
      float s = 0.f;
      #pragma unroll
      for (int cf = 0; cf < 4; cf++) s += __expf(vals[cf] - m);
      #pragma unroll
      for (int msk = 1; msk < 16; msk <<= 1) s += __shfl_xor(s, msk);
      if (llo == 0) part[(size_t)chunk * BDIM + row] = make_float2(m, s);
    }
  }
}

// ---- kernel 3: per-row online-LSE combine over chunks (part is [chunk][row]) ----
__global__ void k_rowreduce(const float2* __restrict__ part,
                            const float* __restrict__ labellogit,
                            float* __restrict__ rowloss) {
  const int row = blockIdx.x;
  const int tid = threadIdx.x;
  float m = -INFINITY, s = 0.f;
  for (int ch = tid; ch < NCHUNK; ch += 256) {
    float2 p = part[(size_t)ch * BDIM + row];
    float nm = fmaxf(m, p.x);
    s = s * __expf(m - nm) + p.y * __expf(p.x - nm);
    m = nm;
  }
  #pragma unroll
  for (int msk = 1; msk < 64; msk <<= 1) {
    float om = __shfl_xor(m, msk), os = __shfl_xor(s, msk);
    float nm = fmaxf(m, om);
    s = s * __expf(m - nm) + os * __expf(om - nm);
    m = nm;
  }
  __shared__ float sm[4], ssum[4];
  const int wv = tid >> 6, ln = tid & 63;
  if (ln == 0) { sm[wv] = m; ssum[wv] = s; }
  __syncthreads();
  if (tid == 0) {
    float M = sm[0], S = ssum[0];
    #pragma unroll
    for (int i = 1; i < 4; i++) {
      float nm = fmaxf(M, sm[i]);
      S = S * __expf(M - nm) + ssum[i] * __expf(sm[i] - nm);
      M = nm;
    }
    rowloss[row] = M + logf(S) - labellogit[row];
  }
}

// ---- kernel 4: mean over rows -> scalar ----
__global__ void k_mean(const float* __restrict__ rowloss, float* __restrict__ out) {
  const int tid = threadIdx.x;
  float v = rowloss[tid];
  #pragma unroll
  for (int msk = 1; msk < 64; msk <<= 1) v += __shfl_xor(v, msk);
  __shared__ float sred[8];
  if ((tid & 63) == 0) sred[tid >> 6] = v;
  __syncthreads();
  if (tid == 0) {
    float s = 0.f;
    #pragma unroll
    for (int i = 0; i < 8; i++) s += sred[i];
    out[0] = s / (float)BDIM;
  }
}

extern "C" void kernel_launch(void* const* d_in, const int* in_sizes, int n_in,
                              void* d_out, int out_size, void* d_ws, size_t ws_size,
                              hipStream_t stream) {
  const float* input = (const float*)d_in[0];
  const long long* label = (const long long*)d_in[1];
  const float* w = (const float*)d_in[2];
  float* out = (float*)d_out;

  char* ws = (char*)d_ws;
  unsigned short* a_bf16 = (unsigned short*)ws;                       // 512 KB
  float2* part = (float2*)(ws + 512 * 1024);                          // NCHUNK*B*8 = 6.4 MB
  float* labellogit = (float*)(ws + 512 * 1024 + (size_t)BDIM * NCHUNK * sizeof(float2));
  float* rowloss = labellogit + BDIM;

  k_rownorm<<<BDIM, 256, 0, stream>>>(input, a_bf16);
  k_main<<<NCHUNK, 512, 0, stream>>>(a_bf16, w, label, part, labellogit);
  k_rowreduce<<<BDIM, 256, 0, stream>>>(part, labellogit, rowloss);
  k_mean<<<1, BDIM, 0, stream>>>(rowloss, out);
}

// Round 3
// 205.603 us; speedup vs baseline: 1.8823x; 1.8823x over previous
//
#include <hip/hip_runtime.h>
#include <hip/hip_bf16.h>
#include <math.h>

#define BDIM 512
#define DDIM 512
#define CDIM 100000
#define NC 64
#define BK 64
#define NSLICE (DDIM / BK)              // 8
#define NCHUNK ((CDIM + NC - 1) / NC)   // 1563

typedef __attribute__((ext_vector_type(8))) short short8;
typedef __attribute__((ext_vector_type(4))) float f32x4;

__device__ __forceinline__ unsigned short f2bf(float f) {
  unsigned int u = __builtin_bit_cast(unsigned int, f);
  u = (u + 0x7FFFu + ((u >> 16) & 1u)) >> 16;   // RNE
  return (unsigned short)u;
}

// ---- kernel 1: L2-normalize feature rows, emit bf16 [B][D] ----
__global__ void k_rownorm(const float* __restrict__ x, unsigned short* __restrict__ a) {
  const int b = blockIdx.x;
  const int tid = threadIdx.x;
  const float* row = x + (size_t)b * DDIM;
  float v0 = row[tid], v1 = row[tid + 256];
  float ss = v0 * v0 + v1 * v1;
  #pragma unroll
  for (int m = 1; m < 64; m <<= 1) ss += __shfl_xor(ss, m);
  __shared__ float sred[4];
  __shared__ float sinv;
  if ((tid & 63) == 0) sred[tid >> 6] = ss;
  __syncthreads();
  if (tid == 0) {
    float s = sred[0] + sred[1] + sred[2] + sred[3];
    sinv = 1.f / fmaxf(sqrtf(s), 1e-12f);
  }
  __syncthreads();
  const float inv = sinv;
  a[(size_t)b * DDIM + tid] = f2bf(v0 * inv);
  a[(size_t)b * DDIM + tid + 256] = f2bf(v1 * inv);
}

// ---- kernel 2: fused colnorm + GEMM + margin + per-chunk LSE partials ----
// 1024 threads / 16 waves, each wave 32 rows x 64 cols (acc = 32 regs).
// Double-buffered BK=64 slices; issue-early / commit-late staging.
__global__ __launch_bounds__(1024)
void k_main(const unsigned short* __restrict__ a,
            const float* __restrict__ w,
            const long long* __restrict__ label,
            float2* __restrict__ part,
            float* __restrict__ labellogit) {
  __shared__ __align__(16) unsigned short wlds[2][NC][BK];  // 2 x 8 KB bf16, XOR-swizzled
  __shared__ float ssred[16][NC];                           // 4 KB
  __shared__ float invwn_sh[NC];

  const int t = threadIdx.x;
  const int chunk = blockIdx.x;
  const int c0 = chunk * NC;
  const bool tailblk = (c0 + NC > CDIM);

  // staging mapping: thread -> (k row dg, 4 consecutive cols cq4); one float4 each
  const int cq4 = (t & 15) * 4;
  const int dg  = t >> 4;          // 0..63
  float ssp0 = 0.f, ssp1 = 0.f, ssp2 = 0.f, ssp3 = 0.f;

  // compute mapping
  const int wave = t >> 6;         // 0..15
  const int lane = t & 63;
  const int lhi = lane >> 4;       // 0..3
  const int llo = lane & 15;       // 0..15

  float4 p0;                        // in-flight slice data
  auto issue = [&](int s) {
    const size_t d0 = (size_t)(s * BK + dg) * CDIM + c0 + cq4;
    if (!tailblk) {
      p0 = *reinterpret_cast<const float4*>(w + d0);
    } else {
      #pragma unroll
      for (int j = 0; j < 4; j++) {
        const bool v = (c0 + cq4 + j) < CDIM;
        p0[j] = v ? w[d0 + j] : 0.f;
      }
    }
  };
  auto commit = [&](int buf) {
    ssp0 += p0.x * p0.x;
    ssp1 += p0.y * p0.y;
    ssp2 += p0.z * p0.z;
    ssp3 += p0.w * p0.w;
    #pragma unroll
    for (int j = 0; j < 4; j++) {
      const int c = cq4 + j;
      wlds[buf][c][dg ^ ((c & 7) << 3)] = f2bf(p0[j]);
    }
  };

  f32x4 acc[2][4];
  #pragma unroll
  for (int i = 0; i < 2; i++)
    #pragma unroll
    for (int j = 0; j < 4; j++)
      acc[i][j] = (f32x4){0.f, 0.f, 0.f, 0.f};

  const unsigned short* ab = a + (size_t)(wave * 32 + llo) * DDIM + (lhi << 3);

  // ---- prologue: stage slice 0 ----
  issue(0);
  commit(0);
  __syncthreads();

  int buf = 0;
  for (int s = 0; s < NSLICE; s++) {
    const bool more = (s + 1 < NSLICE);
    if (more) issue(s + 1);                 // loads in flight across compute

    #pragma unroll
    for (int half = 0; half < 2; half++) {
      const int kk = s * BK + half * 32;
      const int kloc = half * 32 + (lhi << 3);
      short8 af[2], bfr[4];
      #pragma unroll
      for (int rf = 0; rf < 2; rf++)
        af[rf] = *reinterpret_cast<const short8*>(ab + kk + rf * 16 * DDIM);
      #pragma unroll
      for (int cf = 0; cf < 4; cf++) {
        const int c = cf * 16 + llo;
        bfr[cf] = *reinterpret_cast<const short8*>(&wlds[buf][c][kloc ^ ((c & 7) << 3)]);
      }
      #pragma unroll
      for (int rf = 0; rf < 2; rf++)
        #pragma unroll
        for (int cf = 0; cf < 4; cf++)
          acc[rf][cf] = __builtin_amdgcn_mfma_f32_16x16x32_bf16(af[rf], bfr[cf], acc[rf][cf], 0, 0, 0);
    }

    if (more) commit(buf ^ 1);              // vmcnt wait lands after MFMAs
    __syncthreads();
    buf ^= 1;
  }

  // ---- column-norm reduce ----
  // lanes sharing (t & 15) within a wave: xor 16, 32
  #pragma unroll
  for (int msk = 16; msk < 64; msk <<= 1) {
    ssp0 += __shfl_xor(ssp0, msk);
    ssp1 += __shfl_xor(ssp1, msk);
    ssp2 += __shfl_xor(ssp2, msk);
    ssp3 += __shfl_xor(ssp3, msk);
  }
  if (lane < 16)
    *reinterpret_cast<float4*>(&ssred[wave][cq4]) = (float4){ssp0, ssp1, ssp2, ssp3};
  __syncthreads();
  if (t < NC) {
    float s = 0.f;
    #pragma unroll
    for (int i = 0; i < 16; i++) s += ssred[i][t];
    invwn_sh[t] = 1.f / fmaxf(sqrtf(s), 1e-12f);
  }
  __syncthreads();

  // ---- epilogue: logits -> per-row (max, sumexp) over this chunk's 64 classes ----
  #pragma unroll
  for (int rf = 0; rf < 2; rf++) {
    #pragma unroll
    for (int r = 0; r < 4; r++) {
      const int row = wave * 32 + rf * 16 + (lhi << 2) + r;
      const int lab = (int)label[row];
      float vals[4];
      float mloc = -INFINITY;
      #pragma unroll
      for (int cf = 0; cf < 4; cf++) {
        const int cg = c0 + cf * 16 + llo;
        float cs = acc[rf][cf][r] * invwn_sh[cf * 16 + llo];
        cs = fminf(fmaxf(cs, -1.f), 1.f);
        float lg = 64.f * cs;
        if (cg == lab) { lg = 64.f * (cs - 0.35f); labellogit[row] = lg; }
        if (cg >= CDIM) lg = -INFINITY;
        vals[cf] = lg;
        mloc = fmaxf(mloc, lg);
      }
      float m = mloc;
      #pragma unroll
      for (int msk = 1; msk < 16; msk <<= 1) m = fmaxf(m, __shfl_xor(m, msk));
      float s = 0.f;
      #pragma unroll
      for (int cf = 0; cf < 4; cf++) s += __expf(vals[cf] - m);
      #pragma unroll
      for (int msk = 1; msk < 16; msk <<= 1) s += __shfl_xor(s, msk);
      if (llo == 0) part[(size_t)chunk * BDIM + row] = make_float2(m, s);
    }
  }
}

// ---- kernel 3: per-row online-LSE combine over chunks (part is [chunk][row]) ----
__global__ void k_rowreduce(const float2* __restrict__ part,
                            const float* __restrict__ labellogit,
                            float* __restrict__ rowloss) {
  const int row = blockIdx.x;
  const int tid = threadIdx.x;
  float m = -INFINITY, s = 0.f;
  for (int ch = tid; ch < NCHUNK; ch += 256) {
    float2 p = part[(size_t)ch * BDIM + row];
    float nm = fmaxf(m, p.x);
    s = s * __expf(m - nm) + p.y * __expf(p.x - nm);
    m = nm;
  }
  #pragma unroll
  for (int msk = 1; msk < 64; msk <<= 1) {
    float om = __shfl_xor(m, msk), os = __shfl_xor(s, msk);
    float nm = fmaxf(m, om);
    s = s * __expf(m - nm) + os * __expf(om - nm);
    m = nm;
  }
  __shared__ float sm[4], ssum[4];
  const int wv = tid >> 6, ln = tid & 63;
  if (ln == 0) { sm[wv] = m; ssum[wv] = s; }
  __syncthreads();
  if (tid == 0) {
    float M = sm[0], S = ssum[0];
    #pragma unroll
    for (int i = 1; i < 4; i++) {
      float nm = fmaxf(M, sm[i]);
      S = S * __expf(M - nm) + ssum[i] * __expf(sm[i] - nm);
      M = nm;
    }
    rowloss[row] = M + logf(S) - labellogit[row];
  }
}

// ---- kernel 4: mean over rows -> scalar ----
__global__ void k_mean(const float* __restrict__ rowloss, float* __restrict__ out) {
  const int tid = threadIdx.x;
  float v = rowloss[tid];
  #pragma unroll
  for (int msk = 1; msk < 64; msk <<= 1) v += __shfl_xor(v, msk);
  __shared__ float sred[8];
  if ((tid & 63) == 0) sred[tid >> 6] = v;
  __syncthreads();
  if (tid == 0) {
    float s = 0.f;
    #pragma unroll
    for (int i = 0; i < 8; i++) s += sred[i];
    out[0] = s / (float)BDIM;
  }
}

extern "C" void kernel_launch(void* const* d_in, const int* in_sizes, int n_in,
                              void* d_out, int out_size, void* d_ws, size_t ws_size,
                              hipStream_t stream) {
  const float* input = (const float*)d_in[0];
  const long long* label = (const long long*)d_in[1];
  const float* w = (const float*)d_in[2];
  float* out = (float*)d_out;

  char* ws = (char*)d_ws;
  unsigned short* a_bf16 = (unsigned short*)ws;                       // 512 KB
  float2* part = (float2*)(ws + 512 * 1024);                          // NCHUNK*B*8 = 6.4 MB
  float* labellogit = (float*)(ws + 512 * 1024 + (size_t)BDIM * NCHUNK * sizeof(float2));
  float* rowloss = labellogit + BDIM;

  k_rownorm<<<BDIM, 256, 0, stream>>>(input, a_bf16);
  k_main<<<NCHUNK, 1024, 0, stream>>>(a_bf16, w, label, part, labellogit);
  k_rowreduce<<<BDIM, 256, 0, stream>>>(part, labellogit, rowloss);
  k_mean<<<1, BDIM, 0, stream>>>(rowloss, out);
}

// Round 4
// 176.750 us; speedup vs baseline: 2.1896x; 1.1632x over previous
//
#include <hip/hip_runtime.h>
#include <hip/hip_bf16.h>
#include <math.h>

#define BDIM 512
#define DDIM 512
#define CDIM 100000
#define NC 64
#define BK 64
#define NSLICE (DDIM / BK)              // 8
#define NCHUNK ((CDIM + NC - 1) / NC)   // 1563

typedef __attribute__((ext_vector_type(8))) short short8;
typedef __attribute__((ext_vector_type(4))) float f32x4;

__device__ __forceinline__ unsigned short f2bf(float f) {
  unsigned int u = __builtin_bit_cast(unsigned int, f);
  u = (u + 0x7FFFu + ((u >> 16) & 1u)) >> 16;   // RNE
  return (unsigned short)u;
}

__device__ __forceinline__ void gl_lds16(const unsigned short* g, unsigned short* l) {
  __builtin_amdgcn_global_load_lds(
      (const __attribute__((address_space(1))) void*)g,
      (__attribute__((address_space(3))) void*)l, 16, 0, 0);
}

// ---- kernel 1: L2-normalize feature rows, emit bf16 [B][D] ----
__global__ void k_rownorm(const float* __restrict__ x, unsigned short* __restrict__ a) {
  const int b = blockIdx.x;
  const int tid = threadIdx.x;
  const float* row = x + (size_t)b * DDIM;
  float v0 = row[tid], v1 = row[tid + 256];
  float ss = v0 * v0 + v1 * v1;
  #pragma unroll
  for (int m = 1; m < 64; m <<= 1) ss += __shfl_xor(ss, m);
  __shared__ float sred[4];
  __shared__ float sinv;
  if ((tid & 63) == 0) sred[tid >> 6] = ss;
  __syncthreads();
  if (tid == 0) {
    float s = sred[0] + sred[1] + sred[2] + sred[3];
    sinv = 1.f / fmaxf(sqrtf(s), 1e-12f);
  }
  __syncthreads();
  const float inv = sinv;
  a[(size_t)b * DDIM + tid] = f2bf(v0 * inv);
  a[(size_t)b * DDIM + tid + 256] = f2bf(v1 * inv);
}

// ---- kernel 2: fused colnorm + GEMM + margin + per-chunk LSE partials ----
// 512 threads / 8 waves; wave owns 64 rows x 64 cols (acc 4x4).
// A-slice: global_load_lds DMA (pre-swizzled source, linear dest), dbuf.
// B-slice: reg-staged fp32->bf16, conflict-free b32 ds_writes, dbuf.
// One raw s_barrier per slice; counted waits; staging overlaps MFMA phase.
__global__ __launch_bounds__(512)
void k_main(const unsigned short* __restrict__ a,
            const float* __restrict__ w,
            const long long* __restrict__ label,
            float2* __restrict__ part,
            float* __restrict__ labellogit) {
  __shared__ __align__(16) unsigned short alds[2][DDIM * BK];   // 2 x 64 KB
  __shared__ __align__(16) unsigned short blds[2][NC * BK];     // 2 x 8 KB
  __shared__ float ssred[32][NC];                               // 8 KB
  __shared__ float invwn_sh[NC];

  const int t = threadIdx.x;
  const int chunk = blockIdx.x;
  const int c0 = chunk * NC;
  const bool tailblk = (c0 + NC > CDIM);

  const int wave = t >> 6;
  const int lane = t & 63;
  const int lhi = lane >> 4;   // 0..3
  const int llo = lane & 15;   // 0..15

  // A staging: 8 DMA/thread; region r covers 8 rows of 128B each
  const int arsub  = lane >> 3;                 // 0..7 row within region
  const int apiece = (lane & 7) ^ (lane >> 3);  // pre-swizzled 16B piece

  // B staging: thread -> k-pair (2*dgh, 2*dgh+1) x 4 cols (64B segments)
  const int dgh = (t & 127) >> 2;               // 0..31, spread across lanes
  const int bcg = ((t >> 7) << 2) | (t & 3);    // 0..15 col group
  const int bc4 = bcg * 4;

  float4 p0, p1;   // in-flight w data (k=2dgh, 2dgh+1)
  float ssp0 = 0.f, ssp1 = 0.f, ssp2 = 0.f, ssp3 = 0.f;

  auto issueA = [&](int s) {
    #pragma unroll
    for (int i = 0; i < 8; i++) {
      const int r = i * 8 + wave;               // 0..63
      const int row = r * 8 + arsub;            // 0..511
      gl_lds16(a + (size_t)row * DDIM + s * BK + apiece * 8,
               &alds[s & 1][r * 512]);
    }
  };
  auto issueW = [&](int s) {
    const size_t base = (size_t)(s * BK + 2 * dgh) * CDIM + c0 + bc4;
    if (!tailblk) {
      p0 = *reinterpret_cast<const float4*>(w + base);
      p1 = *reinterpret_cast<const float4*>(w + base + CDIM);
    } else {
      #pragma unroll
      for (int j = 0; j < 4; j++) {
        const bool v = (c0 + bc4 + j) < CDIM;
        p0[j] = v ? w[base + j] : 0.f;
        p1[j] = v ? w[base + CDIM + j] : 0.f;
      }
    }
  };
  auto commitW = [&](int s) {
    ssp0 += p0.x * p0.x + p1.x * p1.x;
    ssp1 += p0.y * p0.y + p1.y * p1.y;
    ssp2 += p0.z * p0.z + p1.z * p1.z;
    ssp3 += p0.w * p0.w + p1.w * p1.w;
    unsigned int* b32 = reinterpret_cast<unsigned int*>(&blds[s & 1][0]);
    #pragma unroll
    for (int j = 0; j < 4; j++) {
      const int c = bc4 + j;
      const unsigned int pk = (unsigned int)f2bf(p0[j]) | ((unsigned int)f2bf(p1[j]) << 16);
      // element pair base 2*dgh, elem-XOR ((c&7)<<3)  ->  dword index:
      b32[c * 32 + (dgh ^ ((c & 7) << 2))] = pk;
    }
  };

  f32x4 acc[4][4];
  #pragma unroll
  for (int i = 0; i < 4; i++)
    #pragma unroll
    for (int j = 0; j < 4; j++)
      acc[i][j] = (f32x4){0.f, 0.f, 0.f, 0.f};

  // ---- prologue ----
  issueA(0);
  issueW(0);

  for (int s = 0; s < NSLICE; s++) {
    asm volatile("s_waitcnt vmcnt(0)" ::: "memory");   // slice-s staging arrived
    commitW(s);
    asm volatile("s_waitcnt lgkmcnt(0)" ::: "memory"); // my ds_writes + prior ds_reads done
    __builtin_amdgcn_s_barrier();
    if (s + 1 < NSLICE) { issueA(s + 1); issueW(s + 1); }
    __builtin_amdgcn_sched_barrier(0);

    #pragma unroll
    for (int half = 0; half < 2; half++) {
      short8 af[4], bfr[4];
      #pragma unroll
      for (int rf = 0; rf < 4; rf++) {
        const int row = wave * 64 + rf * 16 + llo;
        af[rf] = *reinterpret_cast<const short8*>(
            &alds[s & 1][row * BK + ((((half << 2) + lhi) ^ (llo & 7)) << 3)]);
      }
      const int kloc = half * 32 + (lhi << 3);
      #pragma unroll
      for (int cf = 0; cf < 4; cf++) {
        const int c = cf * 16 + llo;
        bfr[cf] = *reinterpret_cast<const short8*>(
            &blds[s & 1][c * BK + (kloc ^ ((c & 7) << 3))]);
      }
      #pragma unroll
      for (int rf = 0; rf < 4; rf++)
        #pragma unroll
        for (int cf = 0; cf < 4; cf++)
          acc[rf][cf] = __builtin_amdgcn_mfma_f32_16x16x32_bf16(af[rf], bfr[cf], acc[rf][cf], 0, 0, 0);
    }
  }

  // ---- column-norm reduce (once per block) ----
  #pragma unroll
  for (int j = 0; j < 4; j++) {
    const float sv = (j == 0) ? ssp0 : (j == 1) ? ssp1 : (j == 2) ? ssp2 : ssp3;
    ssred[dgh][bc4 + j] = sv;
  }
  __syncthreads();
  if (t < NC) {
    float s = 0.f;
    #pragma unroll
    for (int i = 0; i < 32; i++) s += ssred[i][t];
    invwn_sh[t] = 1.f / fmaxf(sqrtf(s), 1e-12f);
  }
  __syncthreads();

  // ---- epilogue: logits -> per-row (max, sumexp) over this chunk's 64 classes ----
  #pragma unroll
  for (int rf = 0; rf < 4; rf++) {
    #pragma unroll
    for (int r = 0; r < 4; r++) {
      const int row = wave * 64 + rf * 16 + (lhi << 2) + r;
      const int lab = (int)label[row];
      float vals[4];
      float mloc = -INFINITY;
      #pragma unroll
      for (int cf = 0; cf < 4; cf++) {
        const int cg = c0 + cf * 16 + llo;
        float cs = acc[rf][cf][r] * invwn_sh[cf * 16 + llo];
        cs = fminf(fmaxf(cs, -1.f), 1.f);
        float lg = 64.f * cs;
        if (cg == lab) { lg = 64.f * (cs - 0.35f); labellogit[row] = lg; }
        if (cg >= CDIM) lg = -INFINITY;
        vals[cf] = lg;
        mloc = fmaxf(mloc, lg);
      }
      float m = mloc;
      #pragma unroll
      for (int msk = 1; msk < 16; msk <<= 1) m = fmaxf(m, __shfl_xor(m, msk));
      float s = 0.f;
      #pragma unroll
      for (int cf = 0; cf < 4; cf++) s += __expf(vals[cf] - m);
      #pragma unroll
      for (int msk = 1; msk < 16; msk <<= 1) s += __shfl_xor(s, msk);
      if (llo == 0) part[(size_t)chunk * BDIM + row] = make_float2(m, s);
    }
  }
}

// ---- kernel 3: per-row online-LSE combine over chunks (part is [chunk][row]) ----
__global__ void k_rowreduce(const float2* __restrict__ part,
                            const float* __restrict__ labellogit,
                            float* __restrict__ rowloss) {
  const int row = blockIdx.x;
  const int tid = threadIdx.x;
  float m = -INFINITY, s = 0.f;
  for (int ch = tid; ch < NCHUNK; ch += 256) {
    float2 p = part[(size_t)ch * BDIM + row];
    float nm = fmaxf(m, p.x);
    s = s * __expf(m - nm) + p.y * __expf(p.x - nm);
    m = nm;
  }
  #pragma unroll
  for (int msk = 1; msk < 64; msk <<= 1) {
    float om = __shfl_xor(m, msk), os = __shfl_xor(s, msk);
    float nm = fmaxf(m, om);
    s = s * __expf(m - nm) + os * __expf(om - nm);
    m = nm;
  }
  __shared__ float sm[4], ssum[4];
  const int wv = tid >> 6, ln = tid & 63;
  if (ln == 0) { sm[wv] = m; ssum[wv] = s; }
  __syncthreads();
  if (tid == 0) {
    float M = sm[0], S = ssum[0];
    #pragma unroll
    for (int i = 1; i < 4; i++) {
      float nm = fmaxf(M, sm[i]);
      S = S * __expf(M - nm) + ssum[i] * __expf(sm[i] - nm);
      M = nm;
    }
    rowloss[row] = M + logf(S) - labellogit[row];
  }
}

// ---- kernel 4: mean over rows -> scalar ----
__global__ void k_mean(const float* __restrict__ rowloss, float* __restrict__ out) {
  const int tid = threadIdx.x;
  float v = rowloss[tid];
  #pragma unroll
  for (int msk = 1; msk < 64; msk <<= 1) v += __shfl_xor(v, msk);
  __shared__ float sred[8];
  if ((tid & 63) == 0) sred[tid >> 6] = v;
  __syncthreads();
  if (tid == 0) {
    float s = 0.f;
    #pragma unroll
    for (int i = 0; i < 8; i++) s += sred[i];
    out[0] = s / (float)BDIM;
  }
}

extern "C" void kernel_launch(void* const* d_in, const int* in_sizes, int n_in,
                              void* d_out, int out_size, void* d_ws, size_t ws_size,
                              hipStream_t stream) {
  const float* input = (const float*)d_in[0];
  const long long* label = (const long long*)d_in[1];
  const float* w = (const float*)d_in[2];
  float* out = (float*)d_out;

  char* ws = (char*)d_ws;
  unsigned short* a_bf16 = (unsigned short*)ws;                       // 512 KB
  float2* part = (float2*)(ws + 512 * 1024);                          // NCHUNK*B*8 = 6.4 MB
  float* labellogit = (float*)(ws + 512 * 1024 + (size_t)BDIM * NCHUNK * sizeof(float2));
  float* rowloss = labellogit + BDIM;

  k_rownorm<<<BDIM, 256, 0, stream>>>(input, a_bf16);
  k_main<<<NCHUNK, 512, 0, stream>>>(a_bf16, w, label, part, labellogit);
  k_rowreduce<<<BDIM, 256, 0, stream>>>(part, labellogit, rowloss);
  k_mean<<<1, BDIM, 0, stream>>>(rowloss, out);
}